// Round 2
// baseline (1673.528 us; speedup 1.0000x reference)
//
#include <hip/hip_runtime.h>
#include <hip/hip_bf16.h>
#include <stdint.h>

#define T_DIM 8192
#define E_DIM 1024
#define H_DIM 64

#define BR 16
#define BC 64
#define QT_COUNT (T_DIM / BR)   // 512 q-tiles
#define LDK 68                  // padded LDS stride in floats (16B-aligned rows, 2-way banks max)

// ---------------- projection: O[t][h] = sum_e X[t][e] * W[h][e]  (fp32 in, fp32 out) -------
__global__ __launch_bounds__(256) void proj_kernel(
    const float* __restrict__ Xq, const float* __restrict__ Xk, const float* __restrict__ Xv,
    const float* __restrict__ Wq, const float* __restrict__ Wk, const float* __restrict__ Wv,
    float* __restrict__ Oq, float* __restrict__ Ok, float* __restrict__ Ov)
{
    const float* X; const float* W; float* O;
    if (blockIdx.y == 0)      { X = Xq; W = Wq; O = Oq; }
    else if (blockIdx.y == 1) { X = Xk; W = Wk; O = Ok; }
    else                      { X = Xv; W = Wv; O = Ov; }

    const int tid = threadIdx.x;
    const int h = tid & 63;                      // 0..63 output feature
    const int t = blockIdx.x * 4 + (tid >> 6);   // 4 rows per block

    const float* xr = X + (size_t)t * E_DIM;
    const float* wr = W + (size_t)h * E_DIM;

    float acc = 0.f;
    #pragma unroll 4
    for (int e = 0; e < E_DIM; e += 4) {
        float4 xv = *(const float4*)(xr + e);
        float4 wv = *(const float4*)(wr + e);
        acc += xv.x * wv.x + xv.y * wv.y + xv.z * wv.z + xv.w * wv.w;
    }
    O[(size_t)t * H_DIM + h] = acc;
}

// ---------------- causal flash attention, fp32 scalar ----------------
// block b handles q-tiles b and (511-b): constant work per block (~129 k-tile steps)
__global__ __launch_bounds__(256) void flash_kernel(
    const float* __restrict__ Q, const float* __restrict__ K, const float* __restrict__ V,
    float* __restrict__ Out)
{
    __shared__ __align__(16) float Qs[BR][LDK];
    __shared__ __align__(16) float Ks[BC][LDK];
    __shared__ __align__(16) float Vs[BC][LDK];
    __shared__ __align__(16) float Ps[BR][LDK];

    const int tid = threadIdx.x;
    const int r = tid >> 4;   // 0..15  (q-row within tile)
    const int l = tid & 15;   // 0..15

    for (int pass = 0; pass < 2; ++pass) {
        const int qt = (pass == 0) ? (int)blockIdx.x : (QT_COUNT - 1 - (int)blockIdx.x);
        const int trow = qt * BR + r;

        __syncthreads();  // protect Qs from prior pass's readers

        // load Q tile: 256 float4 = 16 rows x 16 float4
        {
            const int row = tid >> 4, c4 = tid & 15;
            *(float4*)&Qs[row][c4 * 4] = *(const float4*)&Q[(size_t)(qt * BR + row) * H_DIM + c4 * 4];
        }

        float m = -3.0e38f, lsum = 0.f;
        float o0 = 0.f, o1 = 0.f, o2 = 0.f, o3 = 0.f;

        const int ktmax = (qt * BR + BR - 1) / BC;  // inclusive
        for (int kt = 0; kt <= ktmax; ++kt) {
            __syncthreads();  // prior compute done before overwriting K/V
            #pragma unroll
            for (int i = 0; i < 4; ++i) {
                const int idx = tid + 256 * i;
                const int row = idx >> 4, c4 = idx & 15;
                *(float4*)&Ks[row][c4 * 4] = *(const float4*)&K[(size_t)(kt * BC + row) * H_DIM + c4 * 4];
                *(float4*)&Vs[row][c4 * 4] = *(const float4*)&V[(size_t)(kt * BC + row) * H_DIM + c4 * 4];
            }
            __syncthreads();

            // S[r][l + 16j] = Q[r][:] . K[l+16j][:]
            float s0 = 0.f, s1 = 0.f, s2 = 0.f, s3 = 0.f;
            #pragma unroll 4
            for (int d = 0; d < H_DIM; d += 4) {
                float4 qv = *(const float4*)&Qs[r][d];
                float4 k0 = *(const float4*)&Ks[l][d];
                float4 k1 = *(const float4*)&Ks[l + 16][d];
                float4 k2 = *(const float4*)&Ks[l + 32][d];
                float4 k3 = *(const float4*)&Ks[l + 48][d];
                s0 += qv.x * k0.x + qv.y * k0.y + qv.z * k0.z + qv.w * k0.w;
                s1 += qv.x * k1.x + qv.y * k1.y + qv.z * k1.z + qv.w * k1.w;
                s2 += qv.x * k2.x + qv.y * k2.y + qv.z * k2.z + qv.w * k2.w;
                s3 += qv.x * k3.x + qv.y * k3.y + qv.z * k3.z + qv.w * k3.w;
            }

            // scale + causal mask (col > row  ->  -inf); scale = 1/sqrt(64) = 0.125
            const int sbase = kt * BC + l;
            s0 = (sbase        <= trow) ? s0 * 0.125f : -3.0e38f;
            s1 = (sbase + 16   <= trow) ? s1 * 0.125f : -3.0e38f;
            s2 = (sbase + 32   <= trow) ? s2 * 0.125f : -3.0e38f;
            s3 = (sbase + 48   <= trow) ? s3 * 0.125f : -3.0e38f;

            // online softmax: row reduce over the 16 lanes holding this row
            float mt = fmaxf(fmaxf(s0, s1), fmaxf(s2, s3));
            #pragma unroll
            for (int off = 1; off < 16; off <<= 1)
                mt = fmaxf(mt, __shfl_xor(mt, off));
            const float mnew = fmaxf(m, mt);
            const float alpha = __expf(m - mnew);

            const float p0 = __expf(s0 - mnew);
            const float p1 = __expf(s1 - mnew);
            const float p2 = __expf(s2 - mnew);
            const float p3 = __expf(s3 - mnew);

            float ps = p0 + p1 + p2 + p3;
            #pragma unroll
            for (int off = 1; off < 16; off <<= 1)
                ps += __shfl_xor(ps, off);
            lsum = lsum * alpha + ps;
            m = mnew;

            Ps[r][l]      = p0;
            Ps[r][l + 16] = p1;
            Ps[r][l + 32] = p2;
            Ps[r][l + 48] = p3;
            __syncthreads();  // P visible before PV

            // O[r][4l..4l+3] = alpha*O + P[r][:] @ V[:, 4l..4l+3]
            o0 *= alpha; o1 *= alpha; o2 *= alpha; o3 *= alpha;
            #pragma unroll 8
            for (int s = 0; s < BC; ++s) {
                const float p = Ps[r][s];
                float4 vv = *(const float4*)&Vs[s][l * 4];
                o0 += p * vv.x; o1 += p * vv.y; o2 += p * vv.z; o3 += p * vv.w;
            }
        }

        const float inv = 1.f / lsum;
        float4 ov = make_float4(o0 * inv, o1 * inv, o2 * inv, o3 * inv);
        *(float4*)&Out[(size_t)trow * H_DIM + l * 4] = ov;
    }
}

extern "C" void kernel_launch(void* const* d_in, const int* in_sizes, int n_in,
                              void* d_out, int out_size, void* d_ws, size_t ws_size,
                              hipStream_t stream) {
    (void)in_sizes; (void)n_in; (void)out_size; (void)ws_size;
    const float* Xq = (const float*)d_in[0];
    const float* Xk = (const float*)d_in[1];
    const float* Xv = (const float*)d_in[2];
    // d_in[3] = mask: causal triu(k=1), hard-coded in flash_kernel
    const float* Wq = (const float*)d_in[4];
    const float* Wk = (const float*)d_in[5];
    const float* Wv = (const float*)d_in[6];

    float* qws = (float*)d_ws;                    // [8192][64] fp32
    float* kws = qws + (size_t)T_DIM * H_DIM;
    float* vws = kws + (size_t)T_DIM * H_DIM;

    dim3 pgrid(T_DIM / 4, 3);
    proj_kernel<<<pgrid, 256, 0, stream>>>(Xq, Xk, Xv, Wq, Wk, Wv, qws, kws, vws);

    flash_kernel<<<QT_COUNT / 2, 256, 0, stream>>>(qws, kws, vws, (float*)d_out);
}

// Round 3
// 511.040 us; speedup vs baseline: 3.2748x; 3.2748x over previous
//
#include <hip/hip_runtime.h>
#include <hip/hip_bf16.h>
#include <stdint.h>

#define T_DIM 8192
#define E_DIM 1024
#define H_DIM 64
#define NEGF  -3.0e38f

typedef __attribute__((ext_vector_type(8))) short bf16x8;
typedef __attribute__((ext_vector_type(4))) float f32x4;

static __device__ __forceinline__ uint32_t pk2(float x, float y) {
    __hip_bfloat162 h = __float22bfloat162_rn(make_float2(x, y));
    union { __hip_bfloat162 h2; uint32_t u; } c; c.h2 = h; return c.u;
}
static __device__ __forceinline__ bf16x8 pack8(float4 a, float4 b) {
    union { bf16x8 v; uint32_t u[4]; } c;
    c.u[0] = pk2(a.x, a.y); c.u[1] = pk2(a.z, a.w);
    c.u[2] = pk2(b.x, b.y); c.u[3] = pk2(b.z, b.w);
    return c.v;
}
static __device__ __forceinline__ uint16_t bf1(float x) {
    __hip_bfloat16 h = __float2bfloat16(x);
    union { __hip_bfloat16 h1; uint16_t s; } c; c.h1 = h; return c.s;
}

// ============ projection GEMM: O = X @ W^T  (fp32 in -> bf16 out) ============
// wave computes 16 rows x 64 cols; frags read 16B/lane contiguous from global.
// mat 0/1 -> row-major bf16 Q/K; mat 2 -> V transposed to [64][8192] via LDS.
__global__ __launch_bounds__(256) void proj_kernel(
    const float* __restrict__ Xq, const float* __restrict__ Xk, const float* __restrict__ Xv,
    const float* __restrict__ Wq, const float* __restrict__ Wk, const float* __restrict__ Wv,
    uint16_t* __restrict__ Qb, uint16_t* __restrict__ Kb, uint16_t* __restrict__ Vtb)
{
    __shared__ float TD[64][69];   // V-transpose staging (stride 69: <=2-way banks)

    const int mat = blockIdx.y;
    const float* X = (mat == 0) ? Xq : (mat == 1) ? Xk : Xv;
    const float* W = (mat == 0) ? Wq : (mat == 1) ? Wk : Wv;

    const int tid  = threadIdx.x;
    const int wv   = tid >> 6;        // wave 0..3
    const int lane = tid & 63;
    const int lidx = lane & 15;
    const int quad = lane >> 4;
    const int t0   = blockIdx.x * 64 + wv * 16;

    const float* Xr = X + (size_t)(t0 + lidx) * E_DIM + quad * 8;

    f32x4 acc[4] = {{0,0,0,0},{0,0,0,0},{0,0,0,0},{0,0,0,0}};
    for (int k0 = 0; k0 < E_DIM; k0 += 32) {
        float4 x0 = *(const float4*)(Xr + k0);
        float4 x1 = *(const float4*)(Xr + k0 + 4);
        bf16x8 xa = pack8(x0, x1);
        #pragma unroll
        for (int nt = 0; nt < 4; ++nt) {
            const float* Wr = W + (size_t)(nt * 16 + lidx) * E_DIM + k0 + quad * 8;
            float4 w0 = *(const float4*)(Wr);
            float4 w1 = *(const float4*)(Wr + 4);
            bf16x8 wb = pack8(w0, w1);
            acc[nt] = __builtin_amdgcn_mfma_f32_16x16x32_bf16(xa, wb, acc[nt], 0, 0, 0);
        }
    }

    if (mat < 2) {
        uint16_t* O = (mat == 0) ? Qb : Kb;
        #pragma unroll
        for (int nt = 0; nt < 4; ++nt)
            #pragma unroll
            for (int r = 0; r < 4; ++r)
                O[(size_t)(t0 + quad * 4 + r) * H_DIM + nt * 16 + lidx] = bf1(acc[nt][r]);
    } else {
        #pragma unroll
        for (int nt = 0; nt < 4; ++nt)
            #pragma unroll
            for (int r = 0; r < 4; ++r)
                TD[wv * 16 + quad * 4 + r][nt * 16 + lidx] = acc[nt][r];
        __syncthreads();
        const int h = tid >> 2, tq = tid & 3;   // h 0..63, 16 t-values each
        uint32_t w8[8];
        #pragma unroll
        for (int i = 0; i < 8; ++i)
            w8[i] = pk2(TD[tq * 16 + 2 * i][h], TD[tq * 16 + 2 * i + 1][h]);
        uint16_t* dst = Vtb + (size_t)h * T_DIM + blockIdx.x * 64 + tq * 16;
        uint4 lo = make_uint4(w8[0], w8[1], w8[2], w8[3]);
        uint4 hi = make_uint4(w8[4], w8[5], w8[6], w8[7]);
        *(uint4*)dst       = lo;
        *(uint4*)(dst + 8) = hi;
    }
}

// ============ causal flash attention, MFMA bf16 ============
// block = one 16-row q-tile; 4 waves split the key range (contiguous quarters);
// per-wave online softmax; LDS merge of the 4 partials at the end.
__global__ __launch_bounds__(256) void flash_kernel(
    const uint16_t* __restrict__ Qb, const uint16_t* __restrict__ Kb,
    const uint16_t* __restrict__ Vtb, float* __restrict__ Out)
{
    // WS: during k-loop wave-private P tile (rows 0..15 of slice wv);
    // after the loop re-used as the per-wave O partial for the merge.
    __shared__ float WS[4][16][68];
    __shared__ float Mw[4][16];
    __shared__ float Lw[4][16];

    const int tid  = threadIdx.x;
    const int wv   = tid >> 6;
    const int lane = tid & 63;
    const int lidx = lane & 15;
    const int quad = lane >> 4;

    const int qt = 511 - (int)blockIdx.x;   // big tiles first -> better makespan
    const int q0 = qt * 16;

    // Q A-frags, live across whole k-loop
    bf16x8 aq0 = *(const bf16x8*)(Qb + (size_t)(q0 + lidx) * H_DIM + quad * 8);
    bf16x8 aq1 = *(const bf16x8*)(Qb + (size_t)(q0 + lidx) * H_DIM + 32 + quad * 8);

    const int ktiles  = qt / 4 + 1;           // 64-key tiles needed (causal)
    const int base    = ktiles >> 2;
    const int rem     = ktiles & 3;
    const int myn     = base + (wv < rem ? 1 : 0);
    const int mystart = wv * base + (wv < rem ? wv : rem);

    float m[4] = {NEGF, NEGF, NEGF, NEGF};
    float l[4] = {0.f, 0.f, 0.f, 0.f};
    f32x4 o[4] = {{0,0,0,0},{0,0,0,0},{0,0,0,0},{0,0,0,0}};

    for (int it = 0; it < myn; ++it) {
        const int kt = mystart + it;
        const int s0 = kt * 64;

        // ---- S = Q K^T (16 x 64), B-frags straight from L2-resident bf16 K ----
        f32x4 s[4];
        #pragma unroll
        for (int nt = 0; nt < 4; ++nt) {
            const uint16_t* kr = Kb + (size_t)(s0 + nt * 16 + lidx) * H_DIM + quad * 8;
            bf16x8 b0 = *(const bf16x8*)(kr);
            bf16x8 b1 = *(const bf16x8*)(kr + 32);
            f32x4 z = {0, 0, 0, 0};
            s[nt] = __builtin_amdgcn_mfma_f32_16x16x32_bf16(aq0, b0, z, 0, 0, 0);
            s[nt] = __builtin_amdgcn_mfma_f32_16x16x32_bf16(aq1, b1, s[nt], 0, 0, 0);
        }

        // ---- scale + causal mask (only the diagonal tile is partial) ----
        if (kt == ktiles - 1) {
            #pragma unroll
            for (int nt = 0; nt < 4; ++nt)
                #pragma unroll
                for (int r = 0; r < 4; ++r) {
                    const int col = s0 + nt * 16 + lidx;
                    const int row = q0 + quad * 4 + r;
                    s[nt][r] = (col <= row) ? s[nt][r] * 0.125f : NEGF;
                }
        } else {
            #pragma unroll
            for (int nt = 0; nt < 4; ++nt)
                #pragma unroll
                for (int r = 0; r < 4; ++r)
                    s[nt][r] *= 0.125f;
        }

        // ---- online softmax (rows live in 16-lane groups; xor<16 stays inside) ----
        #pragma unroll
        for (int r = 0; r < 4; ++r) {
            float mt = fmaxf(fmaxf(s[0][r], s[1][r]), fmaxf(s[2][r], s[3][r]));
            mt = fmaxf(mt, __shfl_xor(mt, 1));
            mt = fmaxf(mt, __shfl_xor(mt, 2));
            mt = fmaxf(mt, __shfl_xor(mt, 4));
            mt = fmaxf(mt, __shfl_xor(mt, 8));
            const float mn = fmaxf(m[r], mt);
            const float al = __expf(m[r] - mn);
            m[r] = mn;
            float ps = 0.f;
            #pragma unroll
            for (int nt = 0; nt < 4; ++nt) {
                const float pv = __expf(s[nt][r] - mn);
                WS[wv][quad * 4 + r][nt * 16 + lidx] = pv;   // C-layout -> LDS
                ps += pv;
            }
            ps += __shfl_xor(ps, 1);
            ps += __shfl_xor(ps, 2);
            ps += __shfl_xor(ps, 4);
            ps += __shfl_xor(ps, 8);
            l[r] = l[r] * al + ps;
            #pragma unroll
            for (int nt = 0; nt < 4; ++nt) o[nt][r] *= al;
        }

        // ---- P: LDS round-trip to A-layout (wave-private, no barrier needed) ----
        const float* pr = &WS[wv][lidx][0];
        float4 p0 = *(const float4*)(pr + quad * 8);
        float4 p1 = *(const float4*)(pr + quad * 8 + 4);
        float4 p2 = *(const float4*)(pr + 32 + quad * 8);
        float4 p3 = *(const float4*)(pr + 32 + quad * 8 + 4);
        bf16x8 ap0 = pack8(p0, p1);
        bf16x8 ap1 = pack8(p2, p3);

        // ---- O += P V  (V^T rows read 16B/lane from L2) ----
        #pragma unroll
        for (int nt = 0; nt < 4; ++nt) {
            const uint16_t* vr = Vtb + (size_t)(nt * 16 + lidx) * T_DIM + s0 + quad * 8;
            bf16x8 v0 = *(const bf16x8*)(vr);
            bf16x8 v1 = *(const bf16x8*)(vr + 32);
            o[nt] = __builtin_amdgcn_mfma_f32_16x16x32_bf16(ap0, v0, o[nt], 0, 0, 0);
            o[nt] = __builtin_amdgcn_mfma_f32_16x16x32_bf16(ap1, v1, o[nt], 0, 0, 0);
        }
    }

    // ---- publish per-wave partials, merge across the 4 waves ----
    if (lidx == 0) {
        #pragma unroll
        for (int r = 0; r < 4; ++r) { Mw[wv][quad * 4 + r] = m[r]; Lw[wv][quad * 4 + r] = l[r]; }
    }
    #pragma unroll
    for (int nt = 0; nt < 4; ++nt)
        #pragma unroll
        for (int r = 0; r < 4; ++r)
            WS[wv][quad * 4 + r][nt * 16 + lidx] = o[nt][r];
    __syncthreads();

    const int row = tid >> 4, cg = tid & 15;
    float M = fmaxf(fmaxf(Mw[0][row], Mw[1][row]), fmaxf(Mw[2][row], Mw[3][row]));
    float L = 0.f;
    float ox = 0.f, oy = 0.f, oz = 0.f, ow = 0.f;
    #pragma unroll
    for (int w2 = 0; w2 < 4; ++w2) {
        const float sc = __expf(Mw[w2][row] - M);   // empty wave: exp(-3e38)=0
        L += Lw[w2][row] * sc;
        float4 t = *(const float4*)&WS[w2][row][cg * 4];
        ox += t.x * sc; oy += t.y * sc; oz += t.z * sc; ow += t.w * sc;
    }
    const float inv = 1.f / L;
    float4 ov = make_float4(ox * inv, oy * inv, oz * inv, ow * inv);
    *(float4*)(Out + (size_t)(q0 + row) * H_DIM + cg * 4) = ov;
}

extern "C" void kernel_launch(void* const* d_in, const int* in_sizes, int n_in,
                              void* d_out, int out_size, void* d_ws, size_t ws_size,
                              hipStream_t stream) {
    (void)in_sizes; (void)n_in; (void)out_size; (void)ws_size;
    const float* Xq = (const float*)d_in[0];
    const float* Xk = (const float*)d_in[1];
    const float* Xv = (const float*)d_in[2];
    // d_in[3] = mask: causal triu(k=1), hard-coded
    const float* Wq = (const float*)d_in[4];
    const float* Wk = (const float*)d_in[5];
    const float* Wv = (const float*)d_in[6];

    uint16_t* Qb  = (uint16_t*)d_ws;                       // [8192][64] bf16
    uint16_t* Kb  = Qb + (size_t)T_DIM * H_DIM;            // [8192][64] bf16
    uint16_t* Vtb = Kb + (size_t)T_DIM * H_DIM;            // [64][8192] bf16

    dim3 pgrid(T_DIM / 64, 3);
    proj_kernel<<<pgrid, 256, 0, stream>>>(Xq, Xk, Xv, Wq, Wk, Wv, Qb, Kb, Vtb);

    flash_kernel<<<T_DIM / 16, 256, 0, stream>>>(Qb, Kb, Vtb, (float*)d_out);
}

// Round 7
// 490.707 us; speedup vs baseline: 3.4104x; 1.0414x over previous
//
#include <hip/hip_runtime.h>
#include <hip/hip_bf16.h>
#include <stdint.h>

#define T_DIM 8192
#define E_DIM 1024
#define H_DIM 64
#define NEGF  -3.0e38f

typedef __attribute__((ext_vector_type(8))) short bf16x8;
typedef __attribute__((ext_vector_type(4))) float f32x4;

static __device__ __forceinline__ uint32_t pk2(float x, float y) {
    __hip_bfloat162 h = __float22bfloat162_rn(make_float2(x, y));
    union { __hip_bfloat162 h2; uint32_t u; } c; c.h2 = h; return c.u;
}
static __device__ __forceinline__ bf16x8 pack8(float4 a, float4 b) {
    union { bf16x8 v; uint32_t u[4]; } c;
    c.u[0] = pk2(a.x, a.y); c.u[1] = pk2(a.z, a.w);
    c.u[2] = pk2(b.x, b.y); c.u[3] = pk2(b.z, b.w);
    return c.v;
}
static __device__ __forceinline__ uint16_t bf1(float x) {
    __hip_bfloat16 h = __float2bfloat16(x);
    union { __hip_bfloat16 h1; uint16_t s; } c; c.h1 = h; return c.s;
}

// ============ W fp32 -> bf16 pre-conversion (3 x 64 x 1024, one-shot) ============
__global__ __launch_bounds__(256) void wconv_kernel(
    const float* __restrict__ Wq, const float* __restrict__ Wk, const float* __restrict__ Wv,
    uint16_t* __restrict__ Wqb, uint16_t* __restrict__ Wkb, uint16_t* __restrict__ Wvb)
{
    const int idx = blockIdx.x * 256 + threadIdx.x;      // 49152 threads, 4 floats each
    const int which = idx / 16384;                       // 65536 floats per matrix
    const int off = (idx & 16383) * 4;
    const float* W = (which == 0) ? Wq : (which == 1) ? Wk : Wv;
    uint16_t* Wb   = (which == 0) ? Wqb : (which == 1) ? Wkb : Wvb;
    float4 w = *(const float4*)(W + off);
    uint2 o = make_uint2(pk2(w.x, w.y), pk2(w.z, w.w));
    *(uint2*)(Wb + off) = o;
}

// ============ projection GEMM: O = X @ W^T (fp32 X, bf16 W -> bf16 out) ============
// r3 STRUCTURE verbatim (256 thr, 4 waves = 4 t-subtiles, full K per wave);
// ONLY change vs r3: W loaded raw as bf16 (pre-converted by wconv), no pack8.
__global__ __launch_bounds__(256) void proj_kernel(
    const float* __restrict__ Xq, const float* __restrict__ Xk, const float* __restrict__ Xv,
    const uint16_t* __restrict__ Wqb, const uint16_t* __restrict__ Wkb, const uint16_t* __restrict__ Wvb,
    uint16_t* __restrict__ Qb, uint16_t* __restrict__ Kb, uint16_t* __restrict__ Vtb)
{
    __shared__ float TD[64][69];   // V-transpose staging (stride 69: <=2-way banks)

    const int mat = blockIdx.y;
    const float* X    = (mat == 0) ? Xq  : (mat == 1) ? Xk  : Xv;
    const uint16_t* W = (mat == 0) ? Wqb : (mat == 1) ? Wkb : Wvb;

    const int tid  = threadIdx.x;
    const int wv   = tid >> 6;        // wave 0..3 -> t-subtile
    const int lane = tid & 63;
    const int lidx = lane & 15;
    const int quad = lane >> 4;
    const int t0   = blockIdx.x * 64 + wv * 16;

    const float* Xr = X + (size_t)(t0 + lidx) * E_DIM + quad * 8;

    f32x4 acc[4] = {{0,0,0,0},{0,0,0,0},{0,0,0,0},{0,0,0,0}};
    for (int k0 = 0; k0 < E_DIM; k0 += 32) {
        float4 x0 = *(const float4*)(Xr + k0);
        float4 x1 = *(const float4*)(Xr + k0 + 4);
        bf16x8 xa = pack8(x0, x1);
        #pragma unroll
        for (int nt = 0; nt < 4; ++nt) {
            const uint16_t* Wr = W + (size_t)(nt * 16 + lidx) * E_DIM + k0 + quad * 8;
            bf16x8 wb = *(const bf16x8*)Wr;
            acc[nt] = __builtin_amdgcn_mfma_f32_16x16x32_bf16(xa, wb, acc[nt], 0, 0, 0);
        }
    }

    if (mat < 2) {
        uint16_t* O = (mat == 0) ? Qb : Kb;
        #pragma unroll
        for (int nt = 0; nt < 4; ++nt)
            #pragma unroll
            for (int r = 0; r < 4; ++r)
                O[(size_t)(t0 + quad * 4 + r) * H_DIM + nt * 16 + lidx] = bf1(acc[nt][r]);
    } else {
        #pragma unroll
        for (int nt = 0; nt < 4; ++nt)
            #pragma unroll
            for (int r = 0; r < 4; ++r)
                TD[wv * 16 + quad * 4 + r][nt * 16 + lidx] = acc[nt][r];
        __syncthreads();
        const int h = tid >> 2, tq = tid & 3;   // h 0..63, 16 t-values each
        uint32_t w8[8];
        #pragma unroll
        for (int i = 0; i < 8; ++i)
            w8[i] = pk2(TD[tq * 16 + 2 * i][h], TD[tq * 16 + 2 * i + 1][h]);
        uint16_t* dst = Vtb + (size_t)h * T_DIM + blockIdx.x * 64 + tq * 16;
        uint4 lo = make_uint4(w8[0], w8[1], w8[2], w8[3]);
        uint4 hi = make_uint4(w8[4], w8[5], w8[6], w8[7]);
        *(uint4*)dst       = lo;
        *(uint4*)(dst + 8) = hi;
    }
}

// ============ causal flash attention, MFMA bf16 (round-3 verbatim, known-good) ============
__global__ __launch_bounds__(256) void flash_kernel(
    const uint16_t* __restrict__ Qb, const uint16_t* __restrict__ Kb,
    const uint16_t* __restrict__ Vtb, float* __restrict__ Out)
{
    __shared__ __align__(16) float WS[4][16][68];
    __shared__ float Mw[4][16];
    __shared__ float Lw[4][16];

    const int tid  = threadIdx.x;
    const int wv   = tid >> 6;
    const int lane = tid & 63;
    const int lidx = lane & 15;
    const int quad = lane >> 4;

    const int qt = 511 - (int)blockIdx.x;   // big tiles first
    const int q0 = qt * 16;

    // Q A-frags, live across whole k-loop
    bf16x8 aq0 = *(const bf16x8*)(Qb + (size_t)(q0 + lidx) * H_DIM + quad * 8);
    bf16x8 aq1 = *(const bf16x8*)(Qb + (size_t)(q0 + lidx) * H_DIM + 32 + quad * 8);

    const int ktiles  = qt / 4 + 1;
    const int base    = ktiles >> 2;
    const int rem     = ktiles & 3;
    const int myn     = base + (wv < rem ? 1 : 0);
    const int mystart = wv * base + (wv < rem ? wv : rem);

    float m[4] = {NEGF, NEGF, NEGF, NEGF};
    float l[4] = {0.f, 0.f, 0.f, 0.f};
    f32x4 o[4] = {{0,0,0,0},{0,0,0,0},{0,0,0,0},{0,0,0,0}};

    for (int it = 0; it < myn; ++it) {
        const int kt = mystart + it;
        const int s0 = kt * 64;

        // ---- S = Q K^T (16 x 64), B-frags straight from L2-resident bf16 K ----
        f32x4 s[4];
        #pragma unroll
        for (int nt = 0; nt < 4; ++nt) {
            const uint16_t* kr = Kb + (size_t)(s0 + nt * 16 + lidx) * H_DIM + quad * 8;
            bf16x8 b0 = *(const bf16x8*)(kr);
            bf16x8 b1 = *(const bf16x8*)(kr + 32);
            f32x4 z = {0, 0, 0, 0};
            s[nt] = __builtin_amdgcn_mfma_f32_16x16x32_bf16(aq0, b0, z, 0, 0, 0);
            s[nt] = __builtin_amdgcn_mfma_f32_16x16x32_bf16(aq1, b1, s[nt], 0, 0, 0);
        }

        // ---- scale + causal mask (only the diagonal tile is partial) ----
        if (kt == ktiles - 1) {
            #pragma unroll
            for (int nt = 0; nt < 4; ++nt)
                #pragma unroll
                for (int r = 0; r < 4; ++r) {
                    const int col = s0 + nt * 16 + lidx;
                    const int row = q0 + quad * 4 + r;
                    s[nt][r] = (col <= row) ? s[nt][r] * 0.125f : NEGF;
                }
        } else {
            #pragma unroll
            for (int nt = 0; nt < 4; ++nt)
                #pragma unroll
                for (int r = 0; r < 4; ++r)
                    s[nt][r] *= 0.125f;
        }

        // ---- online softmax (rows live in 16-lane groups; xor<16 stays inside) ----
        #pragma unroll
        for (int r = 0; r < 4; ++r) {
            float mt = fmaxf(fmaxf(s[0][r], s[1][r]), fmaxf(s[2][r], s[3][r]));
            mt = fmaxf(mt, __shfl_xor(mt, 1));
            mt = fmaxf(mt, __shfl_xor(mt, 2));
            mt = fmaxf(mt, __shfl_xor(mt, 4));
            mt = fmaxf(mt, __shfl_xor(mt, 8));
            const float mn = fmaxf(m[r], mt);
            const float al = __expf(m[r] - mn);
            m[r] = mn;
            float ps = 0.f;
            #pragma unroll
            for (int nt = 0; nt < 4; ++nt) {
                const float pv = __expf(s[nt][r] - mn);
                WS[wv][quad * 4 + r][nt * 16 + lidx] = pv;   // C-layout -> LDS
                ps += pv;
            }
            ps += __shfl_xor(ps, 1);
            ps += __shfl_xor(ps, 2);
            ps += __shfl_xor(ps, 4);
            ps += __shfl_xor(ps, 8);
            l[r] = l[r] * al + ps;
            #pragma unroll
            for (int nt = 0; nt < 4; ++nt) o[nt][r] *= al;
        }

        // ---- P: LDS round-trip to A-layout (wave-private, no barrier needed) ----
        const float* pr = &WS[wv][lidx][0];
        float4 p0 = *(const float4*)(pr + quad * 8);
        float4 p1 = *(const float4*)(pr + quad * 8 + 4);
        float4 p2 = *(const float4*)(pr + 32 + quad * 8);
        float4 p3 = *(const float4*)(pr + 32 + quad * 8 + 4);
        bf16x8 ap0 = pack8(p0, p1);
        bf16x8 ap1 = pack8(p2, p3);

        // ---- O += P V  (V^T rows read 16B/lane from L2) ----
        #pragma unroll
        for (int nt = 0; nt < 4; ++nt) {
            const uint16_t* vr = Vtb + (size_t)(nt * 16 + lidx) * T_DIM + s0 + quad * 8;
            bf16x8 v0 = *(const bf16x8*)(vr);
            bf16x8 v1 = *(const bf16x8*)(vr + 32);
            o[nt] = __builtin_amdgcn_mfma_f32_16x16x32_bf16(ap0, v0, o[nt], 0, 0, 0);
            o[nt] = __builtin_amdgcn_mfma_f32_16x16x32_bf16(ap1, v1, o[nt], 0, 0, 0);
        }
    }

    // ---- publish per-wave partials, merge across the 4 waves ----
    if (lidx == 0) {
        #pragma unroll
        for (int r = 0; r < 4; ++r) { Mw[wv][quad * 4 + r] = m[r]; Lw[wv][quad * 4 + r] = l[r]; }
    }
    #pragma unroll
    for (int nt = 0; nt < 4; ++nt)
        #pragma unroll
        for (int r = 0; r < 4; ++r)
            WS[wv][quad * 4 + r][nt * 16 + lidx] = o[nt][r];
    __syncthreads();

    const int row = tid >> 4, cg = tid & 15;
    float M = fmaxf(fmaxf(Mw[0][row], Mw[1][row]), fmaxf(Mw[2][row], Mw[3][row]));
    float L = 0.f;
    float ox = 0.f, oy = 0.f, oz = 0.f, ow = 0.f;
    #pragma unroll
    for (int w2 = 0; w2 < 4; ++w2) {
        const float sc = __expf(Mw[w2][row] - M);   // empty wave: exp(-3e38)=0
        L += Lw[w2][row] * sc;
        float4 t = *(const float4*)&WS[w2][row][cg * 4];
        ox += t.x * sc; oy += t.y * sc; oz += t.z * sc; ow += t.w * sc;
    }
    const float inv = 1.f / L;
    float4 ov = make_float4(ox * inv, oy * inv, oz * inv, ow * inv);
    *(float4*)(Out + (size_t)(q0 + row) * H_DIM + cg * 4) = ov;
}

extern "C" void kernel_launch(void* const* d_in, const int* in_sizes, int n_in,
                              void* d_out, int out_size, void* d_ws, size_t ws_size,
                              hipStream_t stream) {
    (void)in_sizes; (void)n_in; (void)out_size; (void)ws_size;
    const float* Xq = (const float*)d_in[0];
    const float* Xk = (const float*)d_in[1];
    const float* Xv = (const float*)d_in[2];
    // d_in[3] = mask: causal triu(k=1), hard-coded
    const float* Wq = (const float*)d_in[4];
    const float* Wk = (const float*)d_in[5];
    const float* Wv = (const float*)d_in[6];

    uint16_t* Qb  = (uint16_t*)d_ws;                       // [8192][64] bf16
    uint16_t* Kb  = Qb + (size_t)T_DIM * H_DIM;            // [8192][64] bf16
    uint16_t* Vtb = Kb + (size_t)T_DIM * H_DIM;            // [64][8192] bf16
    uint16_t* Wqb = Vtb + (size_t)T_DIM * H_DIM;           // [64][1024] bf16 x3
    uint16_t* Wkb = Wqb + (size_t)H_DIM * E_DIM;
    uint16_t* Wvb = Wkb + (size_t)H_DIM * E_DIM;

    wconv_kernel<<<192, 256, 0, stream>>>(Wq, Wk, Wv, Wqb, Wkb, Wvb);

    dim3 pgrid(T_DIM / 64, 3);
    proj_kernel<<<pgrid, 256, 0, stream>>>(Xq, Xk, Xv, Wqb, Wkb, Wvb, Qb, Kb, Vtb);

    flash_kernel<<<T_DIM / 16, 256, 0, stream>>>(Qb, Kb, Vtb, (float*)d_out);
}